// Round 4
// baseline (26.337 us; speedup 1.0000x reference)
//
#include <hip/hip_runtime.h>

typedef __attribute__((ext_vector_type(8))) short bf16x8;
typedef __attribute__((ext_vector_type(4))) float f32x4;

constexpr int KPK = 2304;   // packed symmetrized K (36 blocks of 8x8, f<=g)
constexpr int QK  = 576;    // K per quarter
constexpr int NCH = 18;     // 32-k chunks per quarter

__device__ __forceinline__ unsigned short bf_rne(float f) {
  unsigned u = __float_as_uint(f);
  return (unsigned short)((u + 0x7fffu + ((u >> 16) & 1u)) >> 16);
}

// ---- prepass: symmetrized packed bf16 Wp[o][KPK] (verified rounds 2-3) ----
__global__ __launch_bounds__(256) void wprep_kernel(const float* __restrict__ W,
                                                    unsigned short* __restrict__ Wp) {
  int e = blockIdx.x * 256 + threadIdx.x;   // 576*256 = 147456 = 64*2304
  int o = e / KPK;
  int k = e - o * KPK;
  int kq = k / QK;
  int r = k - kq * QK;
  int j = r >> 6, i = r & 63;
  int run1 = 8 - kq;
  int G, F;
  if (j < run1) { G = 7 - kq; F = j; } else { G = kq; F = j - run1; }
  int f = F * 8 + (i >> 3), g = G * 8 + (i & 7);
  float v = W[o * 4096 + f * 64 + g];
  if (F != G) v += W[o * 4096 + g * 64 + f];
  Wp[o * KPK + k] = bf_rne(v);
}

// ---- main: 512 blocks x 256 thr (4 waves = 4 K-quarters), 64 px/block ----
// 64 KB LDS -> 2 blocks/CU. NO barriers in the K-loop: each wave stages its own
// quarter chunks (global_load_lds ring of 3) and syncs with counted vmcnt only.
__global__ __launch_bounds__(256, 2) void quad_kernel(const float* __restrict__ x,
                                                      const unsigned short* __restrict__ Wp,
                                                      float* __restrict__ out) {
  __shared__ alignas(16) char smem[65536];
  // layout: [0,16K): xT fp32 [f][px^f] swizzled; [16K,64K): Wring[4 waves][3 slots][4 KB]
  // epilogue reuses all 64 KB as red[4 m][4 w][64o x 16px] fp32.
  float* xT = reinterpret_cast<float*>(smem);

  const int t = threadIdx.x;
  const int lane = t & 63;
  const int kq = t >> 6;        // wave id = K quarter
  const int q = lane >> 4;      // k-slice 0..3
  const int r16 = lane & 15;
  const int pxbase = blockIdx.x * 64;

  char* ring = smem + 16384 + kq * 12288;   // this wave's 3-slot ring

  // per-lane W source base: 4 lanes per o-row, 16 B each (64-B chunk rows)
  const char* wsrc = reinterpret_cast<const char*>(Wp) +
                     (lane >> 2) * (KPK * 2) + (lane & 3) * 16 + kq * (QK * 2);

  // issue one 4-KB chunk (64 o-rows x 64 B) into ring slot: 4 x global_load_lds,
  // LDS dest linear (base + lane*16 by HW), fully coalesced 1-KB global segments
  auto issue = [&](int c, int slot) {
    const char* s = wsrc + c * 64;
    char* d = ring + slot * 4096;
#pragma unroll
    for (int i = 0; i < 4; ++i) {
      __builtin_amdgcn_global_load_lds(
          (const __attribute__((address_space(1))) void*)(s + i * (16 * KPK * 2)),
          (__attribute__((address_space(3))) void*)(d + i * 1024), 16, 0, 0);
    }
  };

  issue(0, 0);
  issue(1, 1);

  // x tile -> xT (transposed, XOR word-swizzle; writes 2-way = free) — verified r3
  {
    const float* xg_ = x + (long)pxbase * 64;
#pragma unroll
    for (int c = 0; c < 4; ++c) {
      int e = c * 256 + t;
      int px = e >> 4;
      int f0 = (e & 15) * 4;
      float4 v = *reinterpret_cast<const float4*>(xg_ + px * 64 + f0);
      xT[(f0 + 0) * 64 + (px ^ (f0 + 0))] = v.x;
      xT[(f0 + 1) * 64 + (px ^ (f0 + 1))] = v.y;
      xT[(f0 + 2) * 64 + (px ^ (f0 + 2))] = v.z;
      xT[(f0 + 3) * 64 + (px ^ (f0 + 3))] = v.w;
    }
  }
  __syncthreads();   // xT visible to all waves (also drains chunk 0/1 prefetch - prologue only)

  float xg[4][8];
  auto load_xg = [&](int G) {
#pragma unroll
    for (int m = 0; m < 4; ++m) {
      int px = m * 16 + r16;
#pragma unroll
      for (int b = 0; b < 8; ++b) {
        int row = G * 8 + b;
        xg[m][b] = xT[row * 64 + (px ^ row)];
      }
    }
  };
  const int run1 = 8 - kq;
  load_xg(7 - kq);

  f32x4 acc[4][4] = {};   // [m: 4x16 px][nt: 4x16 o]
  int slot = 0;           // consume slot for chunk j; issue slot for j+2 == (slot+2)%3

  for (int j = 0; j < NCH; ++j) {
    int islot = slot + 2 - ((slot >= 1) ? 3 : 0);    // (slot+2)%3
    if (j + 2 < NCH) issue(j + 2, islot);

    // counted wait: chunk j ready when <= (#loads issued after it) outstanding
    if (j < NCH - 2)       asm volatile("s_waitcnt vmcnt(8)" ::: "memory");
    else if (j == NCH - 2) asm volatile("s_waitcnt vmcnt(4)" ::: "memory");
    else                   asm volatile("s_waitcnt vmcnt(0)" ::: "memory");

    const int s = j & 1;
    const int blk = j >> 1;
    const int F = (blk < run1) ? blk : blk - run1;
    if (j == 2 * run1) load_xg(kq);        // switch to second G-run

    // B fragments: conflict-free without swizzle (64-B rows: bank-quad = (o&1)*4+q)
    const char* wb = ring + slot * 4096;
    bf16x8 bfr[4];
#pragma unroll
    for (int nt = 0; nt < 4; ++nt)
      bfr[nt] = *reinterpret_cast<const bf16x8*>(wb + (nt * 16 + r16) * 64 + q * 16);

    // A fragments: xf * xg in fp32, truncate-pack to bf16
    const int row = F * 8 + s * 4 + q;
    bf16x8 afr[4];
#pragma unroll
    for (int m = 0; m < 4; ++m) {
      float xf = xT[row * 64 + ((m * 16 + r16) ^ row)];
      union { unsigned u[4]; bf16x8 v; } pk;
#pragma unroll
      for (int i = 0; i < 4; ++i) {
        unsigned p0 = __float_as_uint(xf * xg[m][2 * i]);
        unsigned p1 = __float_as_uint(xf * xg[m][2 * i + 1]);
        pk.u[i] = __builtin_amdgcn_perm(p1, p0, 0x07060302u);
      }
      afr[m] = pk.v;
    }

#pragma unroll
    for (int nt = 0; nt < 4; ++nt)
#pragma unroll
      for (int m = 0; m < 4; ++m)
        acc[m][nt] = __builtin_amdgcn_mfma_f32_16x16x32_bf16(afr[m], bfr[nt], acc[m][nt], 0, 0, 0);

    slot = (slot == 2) ? 0 : slot + 1;
  }

  // ---- cross-wave K reduction: red[(m*4+w)][64o x 16px] over the full 64 KB ----
  __syncthreads();   // all waves done with xT + their rings
  float* red = reinterpret_cast<float*>(smem);
#pragma unroll
  for (int m = 0; m < 4; ++m)
#pragma unroll
    for (int nt = 0; nt < 4; ++nt)
      *reinterpret_cast<f32x4*>(red + (m * 4 + kq) * 1024 + (nt * 16 + r16) * 16 + q * 4) =
          acc[m][nt];
  __syncthreads();
  {
    const float* base = red + kq * 4096;   // wave kq reduces m-tile kq
#pragma unroll
    for (int nt = 0; nt < 4; ++nt) {
      int off = (nt * 16 + r16) * 16 + q * 4;
      f32x4 ssum = *reinterpret_cast<const f32x4*>(base + off);
#pragma unroll
      for (int w = 1; w < 4; ++w)
        ssum += *reinterpret_cast<const f32x4*>(base + w * 1024 + off);
      long prow = pxbase + kq * 16 + q * 4;   // D layout: row = q*4+b, col = r16 (verified)
#pragma unroll
      for (int b = 0; b < 4; ++b)
        out[(prow + b) * 64 + nt * 16 + r16] = ssum[b];
    }
  }
}

extern "C" void kernel_launch(void* const* d_in, const int* in_sizes, int n_in,
                              void* d_out, int out_size, void* d_ws, size_t ws_size,
                              hipStream_t stream) {
  const float* x = (const float*)d_in[0];
  const float* W = (const float*)d_in[1];
  float* out = (float*)d_out;
  unsigned short* Wp = (unsigned short*)d_ws;   // 288 KB packed bf16 W

  hipLaunchKernelGGL(wprep_kernel, dim3(576), dim3(256), 0, stream, W, Wp);
  hipLaunchKernelGGL(quad_kernel, dim3(512), dim3(256), 0, stream, x, Wp, out);
}

// Round 5
// 24.089 us; speedup vs baseline: 1.0933x; 1.0933x over previous
//
#include <hip/hip_runtime.h>

typedef __attribute__((ext_vector_type(8))) short bf16x8;
typedef __attribute__((ext_vector_type(4))) float f32x4;

constexpr int KPK = 2304;   // packed symmetrized K (36 blocks of 8x8, f<=g)
constexpr int QK  = 576;    // K per quarter
constexpr int NCH = 18;     // 32-k chunks per quarter

__device__ __forceinline__ unsigned short bf_rne(float f) {
  unsigned u = __float_as_uint(f);
  return (unsigned short)((u + 0x7fffu + ((u >> 16) & 1u)) >> 16);
}

// ---- prepass: symmetrize + pack W into FRAGMENT-LINEAR bf16 layout ----
// Wp ushort index e = ((kq*18 + j)*64 + (q*16 + r16)) * 8 + el
//   holds W_sym[o = nt*16+r16][k = kq*576 + j*32 + q*8 + el]  with nt = bits 9-10 of (e&2047)
// so quad's lane l = q*16+r16 reads a contiguous, lane-linear 1 KB per (j, nt).
__global__ __launch_bounds__(256) void wprep_kernel(const float* __restrict__ W,
                                                    unsigned short* __restrict__ Wp) {
  int e = blockIdx.x * 256 + threadIdx.x;   // 576*256 = 147456 = 72 chunks * 2048
  int c = e & 2047;
  int t2 = e >> 11;          // kq*18 + j
  int kq = t2 / 18;
  int j = t2 - kq * 18;
  int nt = c >> 9;
  int q = (c >> 7) & 3;
  int r16 = (c >> 3) & 15;
  int el = c & 7;
  int o = nt * 16 + r16;
  int kl = j * 32 + q * 8 + el;             // k within quarter (0..575)
  int jblk = kl >> 6, i = kl & 63;
  int run1 = 8 - kq;
  int G, F;
  if (jblk < run1) { G = 7 - kq; F = jblk; } else { G = kq; F = jblk - run1; }
  int f = F * 8 + (i >> 3), g = G * 8 + (i & 7);
  float v = W[o * 4096 + f * 64 + g];
  if (F != G) v += W[o * 4096 + g * 64 + f];
  Wp[e] = bf_rne(v);
}

// ---- main: 256 blocks x 512 thr (8 waves = 2 ph x 4 kq), 128 px/block, 1 block/CU ----
// W streamed straight to VGPRs (3-deep register ring, compiler counted-vmcnt).
// LDS: xT 32 KB (x tile, swizzled) + red 64 KB (epilogue reduction only).
__global__ __launch_bounds__(512, 2) void quad_kernel(const float* __restrict__ x,
                                                      const unsigned short* __restrict__ Wp,
                                                      float* __restrict__ out) {
  __shared__ float xT[8192];                 // [f 64][px 128], word = f*128 + (px^f)
  __shared__ alignas(16) float red[16384];   // 16 regions x 4 KB

  const int t = threadIdx.x;
  const int lane = t & 63;
  const int wv = t >> 6;        // 0..7
  const int kq = wv & 3;        // K quarter
  const int ph = wv >> 2;       // pixel half
  const int q = lane >> 4;      // k-slice 0..3
  const int r16 = lane & 15;
  const int pxbase = blockIdx.x * 128;

  // this wave's B source: quarter kq, lane-linear fragments
  const char* wsrc = reinterpret_cast<const char*>(Wp) + kq * (NCH * 4096) + lane * 16;

  auto loadB = [&](int j, bf16x8 (&b)[4]) {
#pragma unroll
    for (int nt = 0; nt < 4; ++nt)
      b[nt] = *reinterpret_cast<const bf16x8*>(wsrc + j * 4096 + nt * 1024);
  };

  bf16x8 bufs[3][4];
  loadB(0, bufs[0]);
  loadB(1, bufs[1]);
  loadB(2, bufs[2]);

  // x tile -> xT (transposed, XOR word-swizzle; ~2-way write conflicts = free)
  {
    const float* xg_ = x + (long)pxbase * 64;
#pragma unroll
    for (int c = 0; c < 4; ++c) {
      int e4 = c * 512 + t;
      int px = e4 >> 4;            // 0..127
      int f0 = (e4 & 15) * 4;
      float4 v = *reinterpret_cast<const float4*>(xg_ + e4 * 4);
      xT[(f0 + 0) * 128 + (px ^ (f0 + 0))] = v.x;
      xT[(f0 + 1) * 128 + (px ^ (f0 + 1))] = v.y;
      xT[(f0 + 2) * 128 + (px ^ (f0 + 2))] = v.z;
      xT[(f0 + 3) * 128 + (px ^ (f0 + 3))] = v.w;
    }
  }
  __syncthreads();

  float xg[4][8];
  auto load_xg = [&](int G) {
#pragma unroll
    for (int m = 0; m < 4; ++m) {
      int px = ph * 64 + m * 16 + r16;
#pragma unroll
      for (int b = 0; b < 8; ++b) {
        int row = G * 8 + b;
        xg[m][b] = xT[row * 128 + (px ^ row)];
      }
    }
  };
  const int run1 = 8 - kq;
  load_xg(7 - kq);

  f32x4 acc[4][4] = {};   // [m: 4x16 px][nt: 4x16 o]

#pragma unroll
  for (int j = 0; j < NCH; ++j) {
    if (j == 2 * run1) load_xg(kq);          // wave-uniform switch to second G-run
    {
      const int s = j & 1;
      const int blk = j >> 1;
      const int F = (blk < run1) ? blk : blk - run1;
      const int row = F * 8 + s * 4 + q;
      bf16x8 afr[4];
#pragma unroll
      for (int m = 0; m < 4; ++m) {
        float xf = xT[row * 128 + ((ph * 64 + m * 16 + r16) ^ row)];
        union { unsigned u[4]; bf16x8 v; } pk;
#pragma unroll
        for (int i = 0; i < 4; ++i) {
          unsigned p0 = __float_as_uint(xf * xg[m][2 * i]);
          unsigned p1 = __float_as_uint(xf * xg[m][2 * i + 1]);
          pk.u[i] = __builtin_amdgcn_perm(p1, p0, 0x07060302u);   // truncate-pack 2x bf16
        }
        afr[m] = pk.v;
      }
#pragma unroll
      for (int nt = 0; nt < 4; ++nt)
#pragma unroll
        for (int m = 0; m < 4; ++m)
          acc[m][nt] = __builtin_amdgcn_mfma_f32_16x16x32_bf16(afr[m], bufs[j % 3][nt],
                                                               acc[m][nt], 0, 0, 0);
    }
    if (j + 3 < NCH) loadB(j + 3, bufs[j % 3]);   // refill freed buffer (lead = 2 computes)
  }

  // ---- cross-kq reduction: 2 rounds of m-pairs through 64 KB red ----
  // region(ph, mm, w) = ((ph*2 + mm)*4 + w) * 1024 floats; wave (ph,kq) reduces
  // m-tile 2r + (kq>>1), nt-half kq&1.
#pragma unroll
  for (int r = 0; r < 2; ++r) {
    if (r) __syncthreads();                  // round-1 writes wait for round-0 reads
#pragma unroll
    for (int mm = 0; mm < 2; ++mm)
#pragma unroll
      for (int nt = 0; nt < 4; ++nt)
        *reinterpret_cast<f32x4*>(red + ((ph * 2 + mm) * 4 + kq) * 1024 +
                                  (nt * 16 + r16) * 16 + q * 4) = acc[2 * r + mm][nt];
    __syncthreads();
    {
      const int mm2 = kq >> 1;
      const int h = kq & 1;
      const float* base = red + (ph * 2 + mm2) * 4 * 1024;
#pragma unroll
      for (int nh = 0; nh < 2; ++nh) {
        int nt = h * 2 + nh;
        int off = (nt * 16 + r16) * 16 + q * 4;
        f32x4 ssum = *reinterpret_cast<const f32x4*>(base + off);
#pragma unroll
        for (int w = 1; w < 4; ++w)
          ssum += *reinterpret_cast<const f32x4*>(base + w * 1024 + off);
        long prow = pxbase + ph * 64 + (2 * r + mm2) * 16 + q * 4;   // D: row=q*4+b, col=r16
#pragma unroll
        for (int b = 0; b < 4; ++b)
          out[(prow + b) * 64 + nt * 16 + r16] = ssum[b];
      }
    }
  }
}

extern "C" void kernel_launch(void* const* d_in, const int* in_sizes, int n_in,
                              void* d_out, int out_size, void* d_ws, size_t ws_size,
                              hipStream_t stream) {
  const float* x = (const float*)d_in[0];
  const float* W = (const float*)d_in[1];
  float* out = (float*)d_out;
  unsigned short* Wp = (unsigned short*)d_ws;   // 288 KB packed fragment-linear bf16 W

  hipLaunchKernelGGL(wprep_kernel, dim3(576), dim3(256), 0, stream, W, Wp);
  hipLaunchKernelGGL(quad_kernel, dim3(256), dim3(512), 0, stream, x, Wp, out);
}